// Round 1
// baseline (1318.093 us; speedup 1.0000x reference)
//
#include <hip/hip_runtime.h>

#define NVOX 131072
#define KOFF 27
#define PPAIR 32768
#define CIN 64
#define COUT 64
#define PPB 128      // pairs per block
#define FSTR 65      // padded LDS stride for feature tile (bank-conflict-free)

// out[n][c] = bias[c]  (one float4 per thread)
__global__ void init_out_kernel(float* __restrict__ out, const float* __restrict__ bias) {
    int i = blockIdx.x * blockDim.x + threadIdx.x;
    float4 b = ((const float4*)bias)[i & 15];   // (i*4) % 64 selects bias chunk
    ((float4*)out)[i] = b;
}

__global__ __launch_bounds__(256) void sparse_conv_kernel(
    const float* __restrict__ features,
    const float* __restrict__ weight,
    const int* __restrict__ in_map,
    const int* __restrict__ out_map,
    float* __restrict__ out)
{
    __shared__ float Wl[CIN * COUT];     // 16 KB, [i][c] row-major
    __shared__ float Fl[PPB * FSTR];     // 32.5 KB, [pair][i] padded

    const int tid  = threadIdx.x;
    const int k    = blockIdx.x / (PPAIR / PPB);
    const int pb   = blockIdx.x % (PPAIR / PPB);
    const int base = k * PPAIR + pb * PPB;

    // ---- stage weight[k] (4096 floats) via float4 ----
    const float* wk = weight + k * CIN * COUT;
#pragma unroll
    for (int j = 0; j < 4; ++j) {
        int idx = (j * 256 + tid) * 4;
        *(float4*)&Wl[idx] = *(const float4*)&wk[idx];
    }

    // ---- gather 128 feature rows into LDS (zeros for invalid pairs) ----
    const int lane = tid & 63;
    const int rsel = tid >> 6;           // wave-uniform row selector
#pragma unroll 4
    for (int j = 0; j < PPB; j += 4) {
        int row    = j + rsel;
        int in_row = in_map[base + row];     // wave-uniform -> scalar load
        float v = 0.0f;
        if (in_row >= 0) v = features[in_row * CIN + lane];
        Fl[row * FSTR + lane] = v;
    }
    __syncthreads();

    // ---- register-tiled GEMM: thread computes 4 pairs x 8 couts ----
    const int cg = tid & 7;              // cout group (8 couts each)
    const int pg = tid >> 3;             // pair group (4 pairs each), 32 groups

    float acc[4][8];
#pragma unroll
    for (int a = 0; a < 4; ++a)
#pragma unroll
        for (int b = 0; b < 8; ++b) acc[a][b] = 0.0f;

    const float* wbase = &Wl[cg * 8];
    const float* fbase = &Fl[pg * 4 * FSTR];

#pragma unroll 8
    for (int i = 0; i < CIN; ++i) {
        float4 w0 = *(const float4*)&wbase[i * 64];
        float4 w1 = *(const float4*)&wbase[i * 64 + 4];
        float wv[8] = {w0.x, w0.y, w0.z, w0.w, w1.x, w1.y, w1.z, w1.w};
        float fv[4];
#pragma unroll
        for (int a = 0; a < 4; ++a) fv[a] = fbase[a * FSTR + i];
#pragma unroll
        for (int a = 0; a < 4; ++a)
#pragma unroll
            for (int b = 0; b < 8; ++b)
                acc[a][b] = fmaf(fv[a], wv[b], acc[a][b]);
    }

    // ---- scatter-add (skip invalid pairs; HW f32 atomics) ----
#pragma unroll
    for (int a = 0; a < 4; ++a) {
        int pair = pg * 4 + a;
        int orow = out_map[base + pair];
        if (orow >= 0) {
            float* dst = out + orow * COUT + cg * 8;
#pragma unroll
            for (int b = 0; b < 8; ++b)
                unsafeAtomicAdd(dst + b, acc[a][b]);
        }
    }
}

extern "C" void kernel_launch(void* const* d_in, const int* in_sizes, int n_in,
                              void* d_out, int out_size, void* d_ws, size_t ws_size,
                              hipStream_t stream) {
    const float* features = (const float*)d_in[0];
    const float* weight   = (const float*)d_in[1];
    const float* bias     = (const float*)d_in[2];
    const int*   in_map   = (const int*)d_in[3];
    const int*   out_map  = (const int*)d_in[4];
    float*       out      = (float*)d_out;

    int total4 = NVOX * COUT / 4;                 // 2,097,152 float4 stores
    init_out_kernel<<<total4 / 256, 256, 0, stream>>>(out, bias);

    int nblocks = KOFF * (PPAIR / PPB);           // 6912
    sparse_conv_kernel<<<nblocks, 256, 0, stream>>>(features, weight, in_map, out_map, out);
}

// Round 2
// 272.080 us; speedup vs baseline: 4.8445x; 4.8445x over previous
//
#include <hip/hip_runtime.h>
#include <hip/hip_bf16.h>

#define NVOX 131072
#define KOFF 27
#define PPAIR 32768
#define CIN 64
#define COUT 64
#define PPB 128      // pairs per block in conv
#define FSTR 65      // padded LDS stride (bank-conflict-free)
#define TOTP (KOFF * PPAIR)   // 884736 total pairs

// ---- workspace layout (bytes) ----
static constexpr size_t Y_OFF     = 0;
static constexpr size_t Y_BYTES   = (size_t)TOTP * COUT * 2;          // bf16 Y, 113.2 MB
static constexpr size_t CNT_OFF   = Y_OFF + Y_BYTES;
static constexpr size_t START_OFF = CNT_OFF + (size_t)NVOX * 4;
static constexpr size_t CUR_OFF   = START_OFF + ((size_t)NVOX + 256) * 4;
static constexpr size_t SLOT_OFF  = CUR_OFF + (size_t)NVOX * 4;
static constexpr size_t BSUM_OFF  = SLOT_OFF + (size_t)TOTP * 4;
static constexpr size_t BOFF_OFF  = BSUM_OFF + 512 * 4;
static constexpr size_t WS_NEED   = BOFF_OFF + 512 * 4;               // ~118.4 MB

// ================= counting-sort pipeline =================

__global__ void hist_kernel(const int* __restrict__ out_map, int* __restrict__ counts) {
    int t = blockIdx.x * 256 + threadIdx.x;
    int o = out_map[t];
    if (o >= 0) atomicAdd(&counts[o], 1);
}

__global__ void scan1_kernel(const int* __restrict__ counts, int* __restrict__ startv,
                             int* __restrict__ bsum) {
    __shared__ int sm[256];
    int gid = blockIdx.x * 256 + threadIdx.x;
    int v = counts[gid];
    sm[threadIdx.x] = v;
    __syncthreads();
    for (int off = 1; off < 256; off <<= 1) {
        int t = (threadIdx.x >= off) ? sm[threadIdx.x - off] : 0;
        __syncthreads();
        sm[threadIdx.x] += t;
        __syncthreads();
    }
    int incl = sm[threadIdx.x];
    startv[gid] = incl - v;                       // exclusive within block
    if (threadIdx.x == 255) bsum[blockIdx.x] = incl;
}

__global__ void scan2_kernel(const int* __restrict__ bsum, int* __restrict__ boff) {
    __shared__ int sm[512];
    int v = bsum[threadIdx.x];
    sm[threadIdx.x] = v;
    __syncthreads();
    for (int off = 1; off < 512; off <<= 1) {
        int t = (threadIdx.x >= off) ? sm[threadIdx.x - off] : 0;
        __syncthreads();
        sm[threadIdx.x] += t;
        __syncthreads();
    }
    boff[threadIdx.x] = sm[threadIdx.x] - v;      // exclusive
}

__global__ void scan3_kernel(int* __restrict__ startv, int* __restrict__ cursor,
                             const int* __restrict__ boff, const int* __restrict__ counts) {
    int gid = blockIdx.x * 256 + threadIdx.x;
    int v = startv[gid] + boff[blockIdx.x];
    startv[gid] = v;
    cursor[gid] = v;
    if (gid == NVOX - 1) startv[NVOX] = v + counts[gid];
}

__global__ void slot_kernel(const int* __restrict__ out_map, int* __restrict__ cursor,
                            int* __restrict__ slot) {
    int t = blockIdx.x * 256 + threadIdx.x;
    int o = out_map[t];
    slot[t] = (o >= 0) ? atomicAdd(&cursor[o], 1) : -1;
}

// ================= per-offset GEMM (fp32 VALU, verified) =================

__global__ __launch_bounds__(256) void conv_kernel(
    const float* __restrict__ features,
    const float* __restrict__ weight,
    const int* __restrict__ in_map,
    const int* __restrict__ slot,
    __hip_bfloat16* __restrict__ Ybf)
{
    __shared__ float Wl[CIN * COUT];
    __shared__ float Fl[PPB * FSTR];

    const int tid  = threadIdx.x;
    const int k    = blockIdx.x / (PPAIR / PPB);
    const int pb   = blockIdx.x % (PPAIR / PPB);
    const int base = k * PPAIR + pb * PPB;

    const float* wk = weight + k * CIN * COUT;
#pragma unroll
    for (int j = 0; j < 4; ++j) {
        int idx = (j * 256 + tid) * 4;
        *(float4*)&Wl[idx] = *(const float4*)&wk[idx];
    }

    const int lane = tid & 63;
    const int rsel = tid >> 6;
#pragma unroll 4
    for (int j = 0; j < PPB; j += 4) {
        int row    = j + rsel;
        int in_row = in_map[base + row];
        float v = 0.0f;
        if (in_row >= 0) v = features[in_row * CIN + lane];
        Fl[row * FSTR + lane] = v;
    }
    __syncthreads();

    const int cg = tid & 7;
    const int pg = tid >> 3;

    float acc[4][8];
#pragma unroll
    for (int a = 0; a < 4; ++a)
#pragma unroll
        for (int b = 0; b < 8; ++b) acc[a][b] = 0.0f;

    const float* wbase = &Wl[cg * 8];
    const float* fbase = &Fl[pg * 4 * FSTR];

#pragma unroll 8
    for (int i = 0; i < CIN; ++i) {
        float4 w0 = *(const float4*)&wbase[i * 64];
        float4 w1 = *(const float4*)&wbase[i * 64 + 4];
        float wv[8] = {w0.x, w0.y, w0.z, w0.w, w1.x, w1.y, w1.z, w1.w};
        float fv[4];
#pragma unroll
        for (int a = 0; a < 4; ++a) fv[a] = fbase[a * FSTR + i];
#pragma unroll
        for (int a = 0; a < 4; ++a)
#pragma unroll
            for (int b = 0; b < 8; ++b)
                acc[a][b] = fmaf(fv[a], wv[b], acc[a][b]);
    }

    // ---- write sorted Y rows (no atomics) ----
#pragma unroll
    for (int a = 0; a < 4; ++a) {
        int s = slot[base + pg * 4 + a];
        if (s >= 0) {
            union { uint4 u; __hip_bfloat16 h[8]; } pk;
#pragma unroll
            for (int b = 0; b < 8; ++b) pk.h[b] = __float2bfloat16(acc[a][b]);
            *reinterpret_cast<uint4*>(Ybf + (size_t)s * COUT + cg * 8) = pk.u;
        }
    }
}

// ================= per-output-row gather =================

__global__ __launch_bounds__(256) void gather_out_kernel(
    const __hip_bfloat16* __restrict__ Y,
    const int* __restrict__ startv,
    const float* __restrict__ bias,
    float* __restrict__ out)
{
    const int lane = threadIdx.x & 63;
    const int row  = blockIdx.x * 4 + (threadIdx.x >> 6);
    int s0 = startv[row];
    int s1 = startv[row + 1];
    float acc0 = bias[lane];
    float acc1 = 0.0f;
    int j = s0;
    for (; j + 1 < s1; j += 2) {
        acc0 += __bfloat162float(Y[(size_t)j * COUT + lane]);
        acc1 += __bfloat162float(Y[(size_t)(j + 1) * COUT + lane]);
    }
    if (j < s1) acc0 += __bfloat162float(Y[(size_t)j * COUT + lane]);
    out[(size_t)row * COUT + lane] = acc0 + acc1;
}

// ================= fallback (round-1 atomic path, if ws too small) =================

__global__ void init_out_kernel(float* __restrict__ out, const float* __restrict__ bias) {
    int i = blockIdx.x * blockDim.x + threadIdx.x;
    float4 b = ((const float4*)bias)[i & 15];
    ((float4*)out)[i] = b;
}

__global__ __launch_bounds__(256) void conv_atomic_kernel(
    const float* __restrict__ features, const float* __restrict__ weight,
    const int* __restrict__ in_map, const int* __restrict__ out_map,
    float* __restrict__ out)
{
    __shared__ float Wl[CIN * COUT];
    __shared__ float Fl[PPB * FSTR];
    const int tid = threadIdx.x;
    const int k = blockIdx.x / (PPAIR / PPB);
    const int pb = blockIdx.x % (PPAIR / PPB);
    const int base = k * PPAIR + pb * PPB;
    const float* wk = weight + k * CIN * COUT;
#pragma unroll
    for (int j = 0; j < 4; ++j) {
        int idx = (j * 256 + tid) * 4;
        *(float4*)&Wl[idx] = *(const float4*)&wk[idx];
    }
    const int lane = tid & 63;
    const int rsel = tid >> 6;
#pragma unroll 4
    for (int j = 0; j < PPB; j += 4) {
        int row = j + rsel;
        int in_row = in_map[base + row];
        float v = 0.0f;
        if (in_row >= 0) v = features[in_row * CIN + lane];
        Fl[row * FSTR + lane] = v;
    }
    __syncthreads();
    const int cg = tid & 7;
    const int pg = tid >> 3;
    float acc[4][8];
#pragma unroll
    for (int a = 0; a < 4; ++a)
#pragma unroll
        for (int b = 0; b < 8; ++b) acc[a][b] = 0.0f;
    const float* wbase = &Wl[cg * 8];
    const float* fbase = &Fl[pg * 4 * FSTR];
#pragma unroll 8
    for (int i = 0; i < CIN; ++i) {
        float4 w0 = *(const float4*)&wbase[i * 64];
        float4 w1 = *(const float4*)&wbase[i * 64 + 4];
        float wv[8] = {w0.x, w0.y, w0.z, w0.w, w1.x, w1.y, w1.z, w1.w};
        float fv[4];
#pragma unroll
        for (int a = 0; a < 4; ++a) fv[a] = fbase[a * FSTR + i];
#pragma unroll
        for (int a = 0; a < 4; ++a)
#pragma unroll
            for (int b = 0; b < 8; ++b)
                acc[a][b] = fmaf(fv[a], wv[b], acc[a][b]);
    }
#pragma unroll
    for (int a = 0; a < 4; ++a) {
        int pair = pg * 4 + a;
        int orow = out_map[base + pair];
        if (orow >= 0) {
            float* dst = out + orow * COUT + cg * 8;
#pragma unroll
            for (int b = 0; b < 8; ++b) unsafeAtomicAdd(dst + b, acc[a][b]);
        }
    }
}

// ================= launch =================

extern "C" void kernel_launch(void* const* d_in, const int* in_sizes, int n_in,
                              void* d_out, int out_size, void* d_ws, size_t ws_size,
                              hipStream_t stream) {
    const float* features = (const float*)d_in[0];
    const float* weight   = (const float*)d_in[1];
    const float* bias     = (const float*)d_in[2];
    const int*   in_map   = (const int*)d_in[3];
    const int*   out_map  = (const int*)d_in[4];
    float*       out      = (float*)d_out;

    if (ws_size < WS_NEED) {
        // fallback: round-1 atomic path
        int total4 = NVOX * COUT / 4;
        init_out_kernel<<<total4 / 256, 256, 0, stream>>>(out, bias);
        int nblocks = KOFF * (PPAIR / PPB);
        conv_atomic_kernel<<<nblocks, 256, 0, stream>>>(features, weight, in_map, out_map, out);
        return;
    }

    char* ws = (char*)d_ws;
    __hip_bfloat16* Ybf   = (__hip_bfloat16*)(ws + Y_OFF);
    int* counts = (int*)(ws + CNT_OFF);
    int* startv = (int*)(ws + START_OFF);
    int* cursor = (int*)(ws + CUR_OFF);
    int* slot   = (int*)(ws + SLOT_OFF);
    int* bsum   = (int*)(ws + BSUM_OFF);
    int* boff   = (int*)(ws + BOFF_OFF);

    hipMemsetAsync(counts, 0, (size_t)NVOX * 4, stream);

    hist_kernel <<<TOTP / 256, 256, 0, stream>>>(out_map, counts);
    scan1_kernel<<<NVOX / 256, 256, 0, stream>>>(counts, startv, bsum);
    scan2_kernel<<<1, 512, 0, stream>>>(bsum, boff);
    scan3_kernel<<<NVOX / 256, 256, 0, stream>>>(startv, cursor, boff, counts);
    slot_kernel <<<TOTP / 256, 256, 0, stream>>>(out_map, cursor, slot);

    conv_kernel<<<KOFF * (PPAIR / PPB), 256, 0, stream>>>(features, weight, in_map, slot, Ybf);
    gather_out_kernel<<<NVOX / 4, 256, 0, stream>>>(Ybf, startv, bias, out);
}

// Round 3
// 196.082 us; speedup vs baseline: 6.7222x; 1.3876x over previous
//
#include <hip/hip_runtime.h>
#include <hip/hip_bf16.h>

#define NVOX 131072
#define KOFF 27
#define PPAIR 32768
#define CIN 64
#define COUT 64
#define PPB 128
#define FS 72            // padded bf16 stride (144 B = 36 dwords -> conflict-free)
#define TOTP (KOFF * PPAIR)

typedef __attribute__((ext_vector_type(8))) short bf16x8;
typedef __attribute__((ext_vector_type(4))) float f32x4;

// ---- workspace layout (bytes) ----
static constexpr size_t Y_OFF     = 0;
static constexpr size_t Y_BYTES   = (size_t)TOTP * COUT * 2;          // bf16 Y
static constexpr size_t CNT_OFF   = Y_OFF + Y_BYTES;
static constexpr size_t START_OFF = CNT_OFF + (size_t)NVOX * 4;
static constexpr size_t CUR_OFF   = START_OFF + ((size_t)NVOX + 256) * 4;
static constexpr size_t SLOT_OFF  = CUR_OFF + (size_t)NVOX * 4;
static constexpr size_t BSUM_OFF  = SLOT_OFF + (size_t)TOTP * 4;
static constexpr size_t BOFF_OFF  = BSUM_OFF + 512 * 4;
static constexpr size_t WS_NEED   = BOFF_OFF + 512 * 4;

__device__ __forceinline__ unsigned short f2bf(float f) {
    union { __hip_bfloat16 h; unsigned short u; } v;
    v.h = __float2bfloat16(f);
    return v.u;
}
__device__ __forceinline__ float bfbits2f(unsigned int u) {
    union { unsigned int i; float f; } v; v.i = u << 16; return v.f;
}

// ================= counting-sort pipeline =================

__global__ void hist_kernel(const int* __restrict__ out_map, int* __restrict__ counts) {
    int t = blockIdx.x * 256 + threadIdx.x;
    int o = out_map[t];
    if (o >= 0) atomicAdd(&counts[o], 1);
}

__global__ void scan1_kernel(const int* __restrict__ counts, int* __restrict__ startv,
                             int* __restrict__ bsum) {
    __shared__ int sm[256];
    int gid = blockIdx.x * 256 + threadIdx.x;
    int v = counts[gid];
    sm[threadIdx.x] = v;
    __syncthreads();
    for (int off = 1; off < 256; off <<= 1) {
        int t = (threadIdx.x >= off) ? sm[threadIdx.x - off] : 0;
        __syncthreads();
        sm[threadIdx.x] += t;
        __syncthreads();
    }
    int incl = sm[threadIdx.x];
    startv[gid] = incl - v;
    if (threadIdx.x == 255) bsum[blockIdx.x] = incl;
}

__global__ void scan2_kernel(const int* __restrict__ bsum, int* __restrict__ boff) {
    __shared__ int sm[512];
    int v = bsum[threadIdx.x];
    sm[threadIdx.x] = v;
    __syncthreads();
    for (int off = 1; off < 512; off <<= 1) {
        int t = (threadIdx.x >= off) ? sm[threadIdx.x - off] : 0;
        __syncthreads();
        sm[threadIdx.x] += t;
        __syncthreads();
    }
    boff[threadIdx.x] = sm[threadIdx.x] - v;
}

__global__ void scan3_kernel(int* __restrict__ startv, int* __restrict__ cursor,
                             const int* __restrict__ boff, const int* __restrict__ counts) {
    int gid = blockIdx.x * 256 + threadIdx.x;
    int v = startv[gid] + boff[blockIdx.x];
    startv[gid] = v;
    cursor[gid] = v;
    if (gid == NVOX - 1) startv[NVOX] = v + counts[gid];
}

__global__ void slot_kernel(const int* __restrict__ out_map, int* __restrict__ cursor,
                            int* __restrict__ slot) {
    int t = blockIdx.x * 256 + threadIdx.x;
    int o = out_map[t];
    slot[t] = (o >= 0) ? atomicAdd(&cursor[o], 1) : -1;
}

// ================= per-offset GEMM via bf16 MFMA =================

__global__ __launch_bounds__(256) void conv_mfma_kernel(
    const float* __restrict__ features,
    const float* __restrict__ weight,
    const int* __restrict__ in_map,
    const int* __restrict__ slot,
    unsigned short* __restrict__ Ybf)
{
    __shared__ unsigned short Fl[PPB * FS];   // 18432 B, [pair][cin]
    __shared__ unsigned short Wt[COUT * FS];  //  9216 B, [cout][cin] (transposed)

    const int tid  = threadIdx.x;
    const int k    = blockIdx.x / (PPAIR / PPB);
    const int pb   = blockIdx.x % (PPAIR / PPB);
    const int base = k * PPAIR + pb * PPB;

    // ---- stage weight[k] transposed as bf16: Wt[cout][cin] ----
    {
        const float* wk = weight + k * CIN * COUT;
        const int cout = tid & 63;
        const int ci0  = (tid >> 6) * 16;
        union { uint4 u[2]; unsigned short s[16]; } pk;
#pragma unroll
        for (int i = 0; i < 16; ++i)
            pk.s[i] = f2bf(wk[(ci0 + i) * COUT + cout]);
        *(uint4*)&Wt[cout * FS + ci0]     = pk.u[0];
        *(uint4*)&Wt[cout * FS + ci0 + 8] = pk.u[1];
    }

    // ---- gather 128 feature rows -> bf16 LDS (float2 per lane) ----
    {
        const int cin2 = (tid & 31) * 2;
        const int rs   = tid >> 5;            // 8 row-slots
#pragma unroll 4
        for (int j = 0; j < PPB / 8; ++j) {
            int row    = j * 8 + rs;
            int in_row = in_map[base + row];
            unsigned int pkd = 0;
            if (in_row >= 0) {
                float2 v = *(const float2*)&features[(size_t)in_row * CIN + cin2];
                pkd = (unsigned int)f2bf(v.x) | ((unsigned int)f2bf(v.y) << 16);
            }
            *(unsigned int*)&Fl[row * FS + cin2] = pkd;
        }
    }
    __syncthreads();

    // ---- MFMA: wave computes 32 pairs x 64 couts ----
    const int wave = tid >> 6;
    const int l    = tid & 63;
    const int r    = l & 15;
    const int g    = l >> 4;

    bf16x8 af[2][2];    // [mtile][kstep]
    bf16x8 bfr[4][2];   // [ntile][kstep]
#pragma unroll
    for (int m = 0; m < 2; ++m)
#pragma unroll
        for (int s = 0; s < 2; ++s)
            af[m][s] = *(const bf16x8*)&Fl[(wave * 32 + m * 16 + r) * FS + s * 32 + g * 8];
#pragma unroll
    for (int n = 0; n < 4; ++n)
#pragma unroll
        for (int s = 0; s < 2; ++s)
            bfr[n][s] = *(const bf16x8*)&Wt[(n * 16 + r) * FS + s * 32 + g * 8];

    f32x4 acc[2][4];
#pragma unroll
    for (int m = 0; m < 2; ++m)
#pragma unroll
        for (int n = 0; n < 4; ++n)
            acc[m][n] = (f32x4){0.f, 0.f, 0.f, 0.f};

#pragma unroll
    for (int s = 0; s < 2; ++s)
#pragma unroll
        for (int m = 0; m < 2; ++m)
#pragma unroll
            for (int n = 0; n < 4; ++n)
                acc[m][n] = __builtin_amdgcn_mfma_f32_16x16x32_bf16(
                    af[m][s], bfr[n][s], acc[m][n], 0, 0, 0);

    // ---- stage C (bf16) into wave-private Fl rows; no barrier needed ----
    // (wave reads/writes only its own rows [wave*32, wave*32+32))
#pragma unroll
    for (int m = 0; m < 2; ++m)
#pragma unroll
        for (int n = 0; n < 4; ++n) {
#pragma unroll
            for (int j = 0; j < 4; ++j) {
                int pair = wave * 32 + m * 16 + g * 4 + j;
                Fl[pair * FS + n * 16 + r] = f2bf(acc[m][n][j]);
            }
        }

    // ---- copy out: 2 threads per pair, 4x uint4 each half-row ----
    {
        const int p = tid >> 1;
        const int h = tid & 1;
        int s = slot[base + p];
        if (s >= 0) {
            const unsigned short* src = &Fl[p * FS + h * 32];
            uint4* dst = (uint4*)(Ybf + (size_t)s * COUT + h * 32);
            uint4 v0 = *(const uint4*)(src + 0);
            uint4 v1 = *(const uint4*)(src + 8);
            uint4 v2 = *(const uint4*)(src + 16);
            uint4 v3 = *(const uint4*)(src + 24);
            dst[0] = v0; dst[1] = v1; dst[2] = v2; dst[3] = v3;
        }
    }
}

// ================= per-output-row gather (vectorized) =================

__global__ __launch_bounds__(256) void gather_out_kernel(
    const unsigned short* __restrict__ Y,
    const int* __restrict__ startv,
    const float* __restrict__ bias,
    float* __restrict__ out)
{
    const int row  = blockIdx.x * 4 + (threadIdx.x >> 6);
    const int lane = threadIdx.x & 63;
    const int c4   = (lane & 15) * 4;    // 4 couts per lane
    const int grp  = lane >> 4;          // 4 entry groups

    int s0 = startv[row];
    int s1 = startv[row + 1];

    float4 acc = {0.f, 0.f, 0.f, 0.f};
    for (int j = s0 + grp; j < s1; j += 4) {
        uint2 v = *(const uint2*)&Y[(size_t)j * COUT + c4];
        acc.x += bfbits2f(v.x & 0xffffu);
        acc.y += bfbits2f(v.x >> 16);
        acc.z += bfbits2f(v.y & 0xffffu);
        acc.w += bfbits2f(v.y >> 16);
    }
    // reduce across the 4 groups (lanes differing in bits 4,5)
    acc.x += __shfl_xor(acc.x, 16); acc.y += __shfl_xor(acc.y, 16);
    acc.z += __shfl_xor(acc.z, 16); acc.w += __shfl_xor(acc.w, 16);
    acc.x += __shfl_xor(acc.x, 32); acc.y += __shfl_xor(acc.y, 32);
    acc.z += __shfl_xor(acc.z, 32); acc.w += __shfl_xor(acc.w, 32);

    if (grp == 0) {
        float4 b = *(const float4*)&bias[c4];
        float4 rv = {acc.x + b.x, acc.y + b.y, acc.z + b.z, acc.w + b.w};
        *(float4*)&out[(size_t)row * COUT + c4] = rv;
    }
}

// ================= fallback (atomic path, if ws too small) =================

__global__ void init_out_kernel(float* __restrict__ out, const float* __restrict__ bias) {
    int i = blockIdx.x * blockDim.x + threadIdx.x;
    float4 b = ((const float4*)bias)[i & 15];
    ((float4*)out)[i] = b;
}

__global__ __launch_bounds__(256) void conv_atomic_kernel(
    const float* __restrict__ features, const float* __restrict__ weight,
    const int* __restrict__ in_map, const int* __restrict__ out_map,
    float* __restrict__ out)
{
    __shared__ float Wl[CIN * COUT];
    __shared__ float Fl2[PPB * 65];
    const int tid = threadIdx.x;
    const int k = blockIdx.x / (PPAIR / PPB);
    const int pb = blockIdx.x % (PPAIR / PPB);
    const int base = k * PPAIR + pb * PPB;
    const float* wk = weight + k * CIN * COUT;
#pragma unroll
    for (int j = 0; j < 4; ++j) {
        int idx = (j * 256 + tid) * 4;
        *(float4*)&Wl[idx] = *(const float4*)&wk[idx];
    }
    const int lane = tid & 63;
    const int rsel = tid >> 6;
#pragma unroll 4
    for (int j = 0; j < PPB; j += 4) {
        int row = j + rsel;
        int in_row = in_map[base + row];
        float v = 0.0f;
        if (in_row >= 0) v = features[in_row * CIN + lane];
        Fl2[row * 65 + lane] = v;
    }
    __syncthreads();
    const int cg = tid & 7;
    const int pg = tid >> 3;
    float acc[4][8];
#pragma unroll
    for (int a = 0; a < 4; ++a)
#pragma unroll
        for (int b = 0; b < 8; ++b) acc[a][b] = 0.0f;
    const float* wbase = &Wl[cg * 8];
    const float* fbase = &Fl2[pg * 4 * 65];
#pragma unroll 8
    for (int i = 0; i < CIN; ++i) {
        float4 w0 = *(const float4*)&wbase[i * 64];
        float4 w1 = *(const float4*)&wbase[i * 64 + 4];
        float wv[8] = {w0.x, w0.y, w0.z, w0.w, w1.x, w1.y, w1.z, w1.w};
        float fv[4];
#pragma unroll
        for (int a = 0; a < 4; ++a) fv[a] = fbase[a * 65 + i];
#pragma unroll
        for (int a = 0; a < 4; ++a)
#pragma unroll
            for (int b = 0; b < 8; ++b)
                acc[a][b] = fmaf(fv[a], wv[b], acc[a][b]);
    }
#pragma unroll
    for (int a = 0; a < 4; ++a) {
        int pair = pg * 4 + a;
        int orow = out_map[base + pair];
        if (orow >= 0) {
            float* dst = out + orow * COUT + cg * 8;
#pragma unroll
            for (int b = 0; b < 8; ++b) unsafeAtomicAdd(dst + b, acc[a][b]);
        }
    }
}

// ================= launch =================

extern "C" void kernel_launch(void* const* d_in, const int* in_sizes, int n_in,
                              void* d_out, int out_size, void* d_ws, size_t ws_size,
                              hipStream_t stream) {
    const float* features = (const float*)d_in[0];
    const float* weight   = (const float*)d_in[1];
    const float* bias     = (const float*)d_in[2];
    const int*   in_map   = (const int*)d_in[3];
    const int*   out_map  = (const int*)d_in[4];
    float*       out      = (float*)d_out;

    if (ws_size < WS_NEED) {
        int total4 = NVOX * COUT / 4;
        init_out_kernel<<<total4 / 256, 256, 0, stream>>>(out, bias);
        conv_atomic_kernel<<<KOFF * (PPAIR / PPB), 256, 0, stream>>>(
            features, weight, in_map, out_map, out);
        return;
    }

    char* ws = (char*)d_ws;
    unsigned short* Ybf = (unsigned short*)(ws + Y_OFF);
    int* counts = (int*)(ws + CNT_OFF);
    int* startv = (int*)(ws + START_OFF);
    int* cursor = (int*)(ws + CUR_OFF);
    int* slot   = (int*)(ws + SLOT_OFF);
    int* bsum   = (int*)(ws + BSUM_OFF);
    int* boff   = (int*)(ws + BOFF_OFF);

    hipMemsetAsync(counts, 0, (size_t)NVOX * 4, stream);

    hist_kernel <<<TOTP / 256, 256, 0, stream>>>(out_map, counts);
    scan1_kernel<<<NVOX / 256, 256, 0, stream>>>(counts, startv, bsum);
    scan2_kernel<<<1, 512, 0, stream>>>(bsum, boff);
    scan3_kernel<<<NVOX / 256, 256, 0, stream>>>(startv, cursor, boff, counts);
    slot_kernel <<<TOTP / 256, 256, 0, stream>>>(out_map, cursor, slot);

    conv_mfma_kernel<<<KOFF * (PPAIR / PPB), 256, 0, stream>>>(
        features, weight, in_map, slot, Ybf);
    gather_out_kernel<<<NVOX / 4, 256, 0, stream>>>(Ybf, startv, bias, out);
}

// Round 4
// 130.770 us; speedup vs baseline: 10.0795x; 1.4994x over previous
//
#include <hip/hip_runtime.h>
#include <hip/hip_bf16.h>

#define NVOX 131072
#define KOFF 27
#define PPAIR 32768
#define CIN 64
#define COUT 64
#define PPB 128
#define FS 72            // padded bf16 stride (144 B) -> conflict-free fragment reads
#define TOTP (KOFF * PPAIR)

typedef __attribute__((ext_vector_type(8))) short bf16x8;
typedef __attribute__((ext_vector_type(4))) float f32x4;

// ---- workspace layout (bytes), FB last (optional region) ----
static constexpr size_t Y_OFF     = 0;
static constexpr size_t Y_BYTES   = (size_t)TOTP * COUT * 2;            // 113.25 MB
static constexpr size_t SLOT_OFF  = Y_OFF + Y_BYTES;                    // rank, then slot
static constexpr size_t CNT_OFF   = SLOT_OFF + (size_t)TOTP * 4;
static constexpr size_t START_OFF = CNT_OFF + (size_t)NVOX * 4;
static constexpr size_t BSUM_OFF  = START_OFF + ((size_t)NVOX + 64) * 4;
static constexpr size_t BOFF_OFF  = BSUM_OFF + 512 * 4;
static constexpr size_t WIMG_OFF  = BOFF_OFF + 512 * 4;
static constexpr size_t WIMG_BYTES= (size_t)KOFF * COUT * FS * 2;       // 248832
static constexpr size_t FB_OFF    = (WIMG_OFF + WIMG_BYTES + 255) & ~(size_t)255;
static constexpr size_t FB_BYTES  = (size_t)NVOX * CIN * 2;             // 16.78 MB
static constexpr size_t WS_CORE   = FB_OFF;                             // ~118.1 MB
static constexpr size_t WS_FULL   = FB_OFF + FB_BYTES;                  // ~134.9 MB

__device__ __forceinline__ unsigned short f2bf(float f) {
    union { __hip_bfloat16 h; unsigned short u; } v;
    v.h = __float2bfloat16(f);
    return v.u;
}
__device__ __forceinline__ float bfbits2f(unsigned int u) {
    union { unsigned int i; float f; } v; v.i = u << 16; return v.f;
}

// ================= precompute: features -> bf16 =================
__global__ __launch_bounds__(256) void feat2bf_kernel(const float* __restrict__ f,
                                                      unsigned short* __restrict__ fb) {
    int i = blockIdx.x * 256 + threadIdx.x;       // handles 8 floats
    float4 a = ((const float4*)f)[i * 2];
    float4 b = ((const float4*)f)[i * 2 + 1];
    union { uint4 u; unsigned short s[8]; } pk;
    pk.s[0] = f2bf(a.x); pk.s[1] = f2bf(a.y); pk.s[2] = f2bf(a.z); pk.s[3] = f2bf(a.w);
    pk.s[4] = f2bf(b.x); pk.s[5] = f2bf(b.y); pk.s[6] = f2bf(b.z); pk.s[7] = f2bf(b.w);
    ((uint4*)fb)[i] = pk.u;
}

// ================= precompute: weight -> bf16 transposed LDS image =================
// wimg[k][cout][ci] with row stride FS shorts (exact LDS layout)
__global__ __launch_bounds__(256) void wprep_kernel(const float* __restrict__ w,
                                                    unsigned short* __restrict__ wimg) {
    const int k    = blockIdx.x;
    const int t    = threadIdx.x;
    const int cout = t & 63;
    const int ci0  = (t >> 6) * 16;
    const float* wk = w + (size_t)k * CIN * COUT;
    union { uint4 u[2]; unsigned short s[16]; } pk;
#pragma unroll
    for (int i = 0; i < 16; ++i)
        pk.s[i] = f2bf(wk[(ci0 + i) * COUT + cout]);
    unsigned short* dst = wimg + (size_t)k * COUT * FS + cout * FS + ci0;
    *(uint4*)dst       = pk.u[0];
    *(uint4*)(dst + 8) = pk.u[1];
}

// ================= rank (fused hist+slot): counts + within-row rank =================
__global__ void rank_kernel(const int* __restrict__ out_map, int* __restrict__ counts,
                            int* __restrict__ rank) {
    int t = blockIdx.x * 256 + threadIdx.x;
    int o = out_map[t];
    rank[t] = (o >= 0) ? atomicAdd(&counts[o], 1) : -1;
}

// ================= scans =================
__global__ void scan1_kernel(const int* __restrict__ counts, int* __restrict__ startv,
                             int* __restrict__ bsum) {
    __shared__ int sm[256];
    int gid = blockIdx.x * 256 + threadIdx.x;
    int v = counts[gid];
    sm[threadIdx.x] = v;
    __syncthreads();
    for (int off = 1; off < 256; off <<= 1) {
        int t = (threadIdx.x >= off) ? sm[threadIdx.x - off] : 0;
        __syncthreads();
        sm[threadIdx.x] += t;
        __syncthreads();
    }
    int incl = sm[threadIdx.x];
    startv[gid] = incl - v;
    if (threadIdx.x == 255) bsum[blockIdx.x] = incl;
}

__global__ void scan2_kernel(const int* __restrict__ bsum, int* __restrict__ boff) {
    __shared__ int sm[512];
    int v = bsum[threadIdx.x];
    sm[threadIdx.x] = v;
    __syncthreads();
    for (int off = 1; off < 512; off <<= 1) {
        int t = (threadIdx.x >= off) ? sm[threadIdx.x - off] : 0;
        __syncthreads();
        sm[threadIdx.x] += t;
        __syncthreads();
    }
    boff[threadIdx.x] = sm[threadIdx.x] - v;
}

__global__ void scan3_kernel(int* __restrict__ startv, const int* __restrict__ boff,
                             const int* __restrict__ counts) {
    int gid = blockIdx.x * 256 + threadIdx.x;
    int v = startv[gid] + boff[blockIdx.x];
    startv[gid] = v;
    if (gid == NVOX - 1) startv[NVOX] = v + counts[gid];
}

// ================= conv: gather -> MFMA -> sorted-Y write =================
template<bool PREBF>
__global__ __launch_bounds__(256) void conv2_kernel(
    const float* __restrict__ features,            // fp32 (fallback path)
    const unsigned short* __restrict__ featbf,     // bf16 (preferred)
    const unsigned short* __restrict__ wimg,       // [k][cout][ci] stride FS
    const int* __restrict__ in_map,
    const int* __restrict__ out_map,
    const int* __restrict__ startv,
    const int* __restrict__ rank,
    unsigned short* __restrict__ Ybf)
{
    __shared__ unsigned short Fl[PPB * FS];   // 18432 B
    __shared__ unsigned short Wt[COUT * FS];  //  9216 B

    const int tid  = threadIdx.x;
    const int k    = blockIdx.x / (PPAIR / PPB);
    const int pb   = blockIdx.x % (PPAIR / PPB);
    const int base = k * PPAIR + pb * PPB;
    const int wave = tid >> 6;
    const int lane = tid & 63;

    // ---- stage Wt: 9216 B = 9 chunks x (64 lanes x 16 B), wave 0 only ----
    if (wave == 0) {
        const unsigned short* wsrc = wimg + (size_t)k * COUT * FS;
#pragma unroll
        for (int c = 0; c < 9; ++c) {
            __builtin_amdgcn_global_load_lds(
                (const __attribute__((address_space(1))) void*)(wsrc + c * 512 + lane * 8),
                (__attribute__((address_space(3))) void*)(&Wt[c * 512 + lane * 8]),
                16, 0, 0);
        }
    }

    // ---- gather 128 rows: 2 threads/row ----
    {
        const int row = tid >> 1;
        const int h   = tid & 1;
        const int in_row = in_map[base + row];
        if (PREBF) {
            uint4 v0 = {0,0,0,0}, v1 = {0,0,0,0}, v2 = {0,0,0,0}, v3 = {0,0,0,0};
            if (in_row >= 0) {
                const uint4* src = (const uint4*)(featbf + (size_t)in_row * CIN + h * 32);
                v0 = src[0]; v1 = src[1]; v2 = src[2]; v3 = src[3];
            }
            uint4* dst = (uint4*)&Fl[row * FS + h * 32];
            dst[0] = v0; dst[1] = v1; dst[2] = v2; dst[3] = v3;
        } else {
            float4 f[8];
            if (in_row >= 0) {
                const float4* src = (const float4*)(features + (size_t)in_row * CIN + h * 32);
#pragma unroll
                for (int j = 0; j < 8; ++j) f[j] = src[j];
            } else {
#pragma unroll
                for (int j = 0; j < 8; ++j) f[j] = (float4){0.f,0.f,0.f,0.f};
            }
            union { uint4 u[4]; unsigned short s[32]; } pk;
#pragma unroll
            for (int j = 0; j < 8; ++j) {
                pk.s[j*4+0] = f2bf(f[j].x); pk.s[j*4+1] = f2bf(f[j].y);
                pk.s[j*4+2] = f2bf(f[j].z); pk.s[j*4+3] = f2bf(f[j].w);
            }
            uint4* dst = (uint4*)&Fl[row * FS + h * 32];
#pragma unroll
            for (int j = 0; j < 4; ++j) dst[j] = pk.u[j];
        }
    }
    __syncthreads();

    // ---- MFMA: wave computes 32 pairs x 64 couts ----
    const int r = lane & 15;
    const int g = lane >> 4;

    bf16x8 af[2][2];
    bf16x8 bfr[4][2];
#pragma unroll
    for (int m = 0; m < 2; ++m)
#pragma unroll
        for (int s = 0; s < 2; ++s)
            af[m][s] = *(const bf16x8*)&Fl[(wave * 32 + m * 16 + r) * FS + s * 32 + g * 8];
#pragma unroll
    for (int n = 0; n < 4; ++n)
#pragma unroll
        for (int s = 0; s < 2; ++s)
            bfr[n][s] = *(const bf16x8*)&Wt[(n * 16 + r) * FS + s * 32 + g * 8];

    f32x4 acc[2][4];
#pragma unroll
    for (int m = 0; m < 2; ++m)
#pragma unroll
        for (int n = 0; n < 4; ++n)
            acc[m][n] = (f32x4){0.f, 0.f, 0.f, 0.f};

#pragma unroll
    for (int s = 0; s < 2; ++s)
#pragma unroll
        for (int m = 0; m < 2; ++m)
#pragma unroll
            for (int n = 0; n < 4; ++n)
                acc[m][n] = __builtin_amdgcn_mfma_f32_16x16x32_bf16(
                    af[m][s], bfr[n][s], acc[m][n], 0, 0, 0);

    // ---- stage C (bf16) into wave-private Fl rows ----
#pragma unroll
    for (int m = 0; m < 2; ++m)
#pragma unroll
        for (int n = 0; n < 4; ++n) {
#pragma unroll
            for (int j = 0; j < 4; ++j) {
                int pair = wave * 32 + m * 16 + g * 4 + j;
                Fl[pair * FS + n * 16 + r] = f2bf(acc[m][n][j]);
            }
        }

    // ---- copy out: 2 threads/pair (wave-private rows), slot = startv[o]+rank ----
    {
        const int p = tid >> 1;
        const int h = tid & 1;
        int o = out_map[base + p];
        if (o >= 0) {
            int s = startv[o] + rank[base + p];
            const unsigned short* src = &Fl[p * FS + h * 32];
            uint4* dst = (uint4*)(Ybf + (size_t)s * COUT + h * 32);
            uint4 v0 = *(const uint4*)(src + 0);
            uint4 v1 = *(const uint4*)(src + 8);
            uint4 v2 = *(const uint4*)(src + 16);
            uint4 v3 = *(const uint4*)(src + 24);
            dst[0] = v0; dst[1] = v1; dst[2] = v2; dst[3] = v3;
        }
    }
}

// ================= per-output-row gather =================
__global__ __launch_bounds__(256) void gather_out_kernel(
    const unsigned short* __restrict__ Y,
    const int* __restrict__ startv,
    const float* __restrict__ bias,
    float* __restrict__ out)
{
    const int row  = blockIdx.x * 4 + (threadIdx.x >> 6);
    const int lane = threadIdx.x & 63;
    const int c4   = (lane & 15) * 4;
    const int grp  = lane >> 4;

    int s0 = startv[row];
    int s1 = startv[row + 1];

    float4 acc = {0.f, 0.f, 0.f, 0.f};
    for (int j = s0 + grp; j < s1; j += 4) {
        uint2 v = *(const uint2*)&Y[(size_t)j * COUT + c4];
        acc.x += bfbits2f(v.x & 0xffffu);
        acc.y += bfbits2f(v.x >> 16);
        acc.z += bfbits2f(v.y & 0xffffu);
        acc.w += bfbits2f(v.y >> 16);
    }
    acc.x += __shfl_xor(acc.x, 16); acc.y += __shfl_xor(acc.y, 16);
    acc.z += __shfl_xor(acc.z, 16); acc.w += __shfl_xor(acc.w, 16);
    acc.x += __shfl_xor(acc.x, 32); acc.y += __shfl_xor(acc.y, 32);
    acc.z += __shfl_xor(acc.z, 32); acc.w += __shfl_xor(acc.w, 32);

    if (grp == 0) {
        float4 b = *(const float4*)&bias[c4];
        float4 rv = {acc.x + b.x, acc.y + b.y, acc.z + b.z, acc.w + b.w};
        *(float4*)&out[(size_t)row * COUT + c4] = rv;
    }
}

// ================= tiny-ws fallback (round-1 atomic path) =================
__global__ void init_out_kernel(float* __restrict__ out, const float* __restrict__ bias) {
    int i = blockIdx.x * blockDim.x + threadIdx.x;
    float4 b = ((const float4*)bias)[i & 15];
    ((float4*)out)[i] = b;
}

__global__ __launch_bounds__(256) void conv_atomic_kernel(
    const float* __restrict__ features, const float* __restrict__ weight,
    const int* __restrict__ in_map, const int* __restrict__ out_map,
    float* __restrict__ out)
{
    __shared__ float Wl[CIN * COUT];
    __shared__ float Fl2[PPB * 65];
    const int tid = threadIdx.x;
    const int k = blockIdx.x / (PPAIR / PPB);
    const int pb = blockIdx.x % (PPAIR / PPB);
    const int base = k * PPAIR + pb * PPB;
    const float* wk = weight + k * CIN * COUT;
#pragma unroll
    for (int j = 0; j < 4; ++j) {
        int idx = (j * 256 + tid) * 4;
        *(float4*)&Wl[idx] = *(const float4*)&wk[idx];
    }
    const int lane = tid & 63;
    const int rsel = tid >> 6;
#pragma unroll 4
    for (int j = 0; j < PPB; j += 4) {
        int row = j + rsel;
        int in_row = in_map[base + row];
        float v = 0.0f;
        if (in_row >= 0) v = features[in_row * CIN + lane];
        Fl2[row * 65 + lane] = v;
    }
    __syncthreads();
    const int cg = tid & 7;
    const int pg = tid >> 3;
    float acc[4][8];
#pragma unroll
    for (int a = 0; a < 4; ++a)
#pragma unroll
        for (int b = 0; b < 8; ++b) acc[a][b] = 0.0f;
    const float* wbase = &Wl[cg * 8];
    const float* fbase = &Fl2[pg * 4 * 65];
#pragma unroll 8
    for (int i = 0; i < CIN; ++i) {
        float4 w0 = *(const float4*)&wbase[i * 64];
        float4 w1 = *(const float4*)&wbase[i * 64 + 4];
        float wv[8] = {w0.x, w0.y, w0.z, w0.w, w1.x, w1.y, w1.z, w1.w};
        float fv[4];
#pragma unroll
        for (int a = 0; a < 4; ++a) fv[a] = fbase[a * 65 + i];
#pragma unroll
        for (int a = 0; a < 4; ++a)
#pragma unroll
            for (int b = 0; b < 8; ++b)
                acc[a][b] = fmaf(fv[a], wv[b], acc[a][b]);
    }
#pragma unroll
    for (int a = 0; a < 4; ++a) {
        int pair = pg * 4 + a;
        int orow = out_map[base + pair];
        if (orow >= 0) {
            float* dst = out + orow * COUT + cg * 8;
#pragma unroll
            for (int b = 0; b < 8; ++b) unsafeAtomicAdd(dst + b, acc[a][b]);
        }
    }
}

// ================= launch =================
extern "C" void kernel_launch(void* const* d_in, const int* in_sizes, int n_in,
                              void* d_out, int out_size, void* d_ws, size_t ws_size,
                              hipStream_t stream) {
    const float* features = (const float*)d_in[0];
    const float* weight   = (const float*)d_in[1];
    const float* bias     = (const float*)d_in[2];
    const int*   in_map   = (const int*)d_in[3];
    const int*   out_map  = (const int*)d_in[4];
    float*       out      = (float*)d_out;

    if (ws_size < WS_CORE) {
        int total4 = NVOX * COUT / 4;
        init_out_kernel<<<total4 / 256, 256, 0, stream>>>(out, bias);
        conv_atomic_kernel<<<KOFF * (PPAIR / PPB), 256, 0, stream>>>(
            features, weight, in_map, out_map, out);
        return;
    }

    char* ws = (char*)d_ws;
    unsigned short* Ybf  = (unsigned short*)(ws + Y_OFF);
    int* rank   = (int*)(ws + SLOT_OFF);
    int* counts = (int*)(ws + CNT_OFF);
    int* startv = (int*)(ws + START_OFF);
    int* bsum   = (int*)(ws + BSUM_OFF);
    int* boff   = (int*)(ws + BOFF_OFF);
    unsigned short* wimg = (unsigned short*)(ws + WIMG_OFF);
    unsigned short* fb   = (unsigned short*)(ws + FB_OFF);
    const bool prebf = (ws_size >= WS_FULL);

    hipMemsetAsync(counts, 0, (size_t)NVOX * 4, stream);

    wprep_kernel<<<KOFF, 256, 0, stream>>>(weight, wimg);
    if (prebf)
        feat2bf_kernel<<<NVOX * CIN / 8 / 256, 256, 0, stream>>>(features, fb);

    rank_kernel <<<TOTP / 256, 256, 0, stream>>>(out_map, counts, rank);
    scan1_kernel<<<NVOX / 256, 256, 0, stream>>>(counts, startv, bsum);
    scan2_kernel<<<1, 512, 0, stream>>>(bsum, boff);
    scan3_kernel<<<NVOX / 256, 256, 0, stream>>>(startv, boff, counts);

    if (prebf)
        conv2_kernel<true><<<KOFF * (PPAIR / PPB), 256, 0, stream>>>(
            features, fb, wimg, in_map, out_map, startv, rank, Ybf);
    else
        conv2_kernel<false><<<KOFF * (PPAIR / PPB), 256, 0, stream>>>(
            features, fb, wimg, in_map, out_map, startv, rank, Ybf);

    gather_out_kernel<<<NVOX / 4, 256, 0, stream>>>(Ybf, startv, bias, out);
}